// Round 9
// baseline (1548.379 us; speedup 1.0000x reference)
//
#include <hip/hip_runtime.h>
#include <hip/hip_bf16.h>
#include <math.h>

#define N_NODES 200000
#define T_TREES 2000
#define S_NODES 100
#define F_DIM 256
#define H_DIM 256
#define G_DIM 768   // 3*H
#define D_MAX 28    // upper bound on depth layers (actual ~16)

typedef __attribute__((ext_vector_type(8))) short short8b;   // 8 bf16 = 4 VGPR
typedef __attribute__((ext_vector_type(4))) float f32x4;

static __device__ __forceinline__ unsigned short f2bf(float x) {
    union { __hip_bfloat16 h; unsigned short u; } cv;
    cv.h = __float2bfloat16(x);
    return cv.u;
}
static __device__ __forceinline__ float bf2f(unsigned short u) {
    return __uint_as_float(((unsigned)u) << 16);
}

// ---------------------------------------------------------------------------
__global__ void k_zero(float4* __restrict__ p, int n4) {
    float4 z = make_float4(0.f, 0.f, 0.f, 0.f);
    for (int i = blockIdx.x * blockDim.x + threadIdx.x; i < n4;
         i += gridDim.x * blockDim.x)
        p[i] = z;
}

// x (fp32) -> bf16, 8 elems/thread
__global__ void k_convx(const float* __restrict__ x, unsigned short* __restrict__ xb,
                        int n8) {
    for (int i = blockIdx.x * blockDim.x + threadIdx.x; i < n8;
         i += gridDim.x * blockDim.x) {
        const float4* px = (const float4*)(x + (size_t)i * 8);
        float4 u = px[0], v = px[1];
        short8b t;
        t[0] = f2bf(u.x); t[1] = f2bf(u.y); t[2] = f2bf(u.z); t[3] = f2bf(u.w);
        t[4] = f2bf(v.x); t[5] = f2bf(v.y); t[6] = f2bf(v.z); t[7] = f2bf(v.w);
        *(short8b*)(xb + (size_t)i * 8) = t;
    }
}

// M = min{ p >= T : layer_nodes[p] < N } (layer 0 is exactly the T roots)
__global__ void k_findM(const int* __restrict__ ln, int LM, int* __restrict__ Mdev) {
    int local = 0x7F7F7F7F;
    for (int p = T_TREES + blockIdx.x * blockDim.x + threadIdx.x; p < LM;
         p += gridDim.x * blockDim.x)
        if (ln[p] < N_NODES && p < local) local = p;
#pragma unroll
    for (int off = 32; off; off >>= 1) {
        int o = __shfl_down(local, off);
        if (o < local) local = o;
    }
    __shared__ int wmin[4];
    if ((threadIdx.x & 63) == 0) wmin[threadIdx.x >> 6] = local;
    __syncthreads();
    if (threadIdx.x == 0) {
        int m = wmin[0];
        for (int i = 1; i < 4; ++i) if (wmin[i] < m) m = wmin[i];
        if (m < 0x7F7F7F7F) atomicMin(Mdev, m);
    }
}

// layer_cnt[d] = #valid nodes in layer d (valid entries are a row prefix)
__global__ void k_hist(const int* __restrict__ ln, const int* __restrict__ Mdev,
                       int* __restrict__ layer_cnt, int LM) {
    __shared__ int h[D_MAX];
    if (threadIdx.x < D_MAX) h[threadIdx.x] = 0;
    __syncthreads();
    const int M = Mdev[0];
    for (int p = blockIdx.x * blockDim.x + threadIdx.x; p < LM;
         p += gridDim.x * blockDim.x)
        if (ln[p] < N_NODES) {
            int d = p / M;
            if (d < D_MAX) atomicAdd(&h[d], 1);
        }
    __syncthreads();
    if (threadIdx.x < D_MAX && h[threadIdx.x])
        atomicAdd(&layer_cnt[threadIdx.x], h[threadIdx.x]);
}

// Weights fp32 -> bf16 (row-major [g][k])
__global__ void k_convw(const float* __restrict__ wi, const float* __restrict__ wh,
                        unsigned short* __restrict__ wib, unsigned short* __restrict__ whb) {
    int i = blockIdx.x * blockDim.x + threadIdx.x;
    if (i < G_DIM * F_DIM) {
        wib[i] = f2bf(wi[i]);
        whb[i] = f2bf(wh[i]);
    }
}

// ---------------------------------------------------------------------------
// One-shot GEMM (unchanged from round 8): gi_all[m][g] = xb@w_ih^T + b_ih (bf16)
// ---------------------------------------------------------------------------
__global__ __launch_bounds__(256) void k_gemm_x(
    const unsigned short* __restrict__ xb,
    const unsigned short* __restrict__ wib,
    const float* __restrict__ b_ih,
    unsigned short* __restrict__ gi_all) {
    __shared__ unsigned short Bs[2][64][256];

    const int tid = threadIdx.x;
    const int wv = tid >> 6, lane = tid & 63;
    const int lr = lane & 15, kg = lane >> 4;
    const long m0 = (long)blockIdx.x * 128 + wv * 32;

    short8b A[2][8];
#pragma unroll
    for (int ms = 0; ms < 2; ++ms) {
        long r = m0 + ms * 16 + lr;
        if (r > N_NODES - 1) r = N_NODES - 1;
        const unsigned short* xp = xb + r * F_DIM + kg * 8;
#pragma unroll
        for (int ks = 0; ks < 8; ++ks)
            A[ms][ks] = *(const short8b*)(xp + ks * 32);
    }

    const int sr = tid >> 2, sp = tid & 3;
    const int psr = (sr >> 3) & 1;
    const int gp_off = (lr >> 2) * 8 + (lr & 3);
    const int prow = (gp_off >> 3) & 1;

    short8b st[8];
    {
        const unsigned short* src = wib + (size_t)sr * F_DIM;
#pragma unroll
        for (int q = 0; q < 4; ++q) {
            int c = sp * 16 + q * 64;
            st[2 * q]     = *(const short8b*)(src + c);
            st[2 * q + 1] = *(const short8b*)(src + c + 8);
        }
#pragma unroll
        for (int q = 0; q < 4; ++q) {
            int slot = (sp >> 1) + 2 * q;
            int pc = ((slot ^ psr) << 5) + (sp & 1) * 16;
            *(short8b*)&Bs[0][sr][pc]     = st[2 * q];
            *(short8b*)&Bs[0][sr][pc + 8] = st[2 * q + 1];
        }
    }
    __syncthreads();

    const f32x4 zf = {0.f, 0.f, 0.f, 0.f};

    for (int nt = 0; nt < 12; ++nt) {
        const int cur = nt & 1;
        if (nt < 11) {
            const unsigned short* src = wib + (size_t)((nt + 1) * 64 + sr) * F_DIM;
#pragma unroll
            for (int q = 0; q < 4; ++q) {
                int c = sp * 16 + q * 64;
                st[2 * q]     = *(const short8b*)(src + c);
                st[2 * q + 1] = *(const short8b*)(src + c + 8);
            }
        }
#pragma unroll
        for (int nsp = 0; nsp < 2; ++nsp) {
            f32x4 aP0 = zf, aQ0 = zf, aP1 = zf, aQ1 = zf;
            const int rP = nsp * 32 + gp_off;
#pragma unroll
            for (int ks = 0; ks < 8; ++ks) {
                const int pc = ((ks ^ prow) << 5) + kg * 8;
                short8b BP = *(const short8b*)&Bs[cur][rP][pc];
                short8b BQ = *(const short8b*)&Bs[cur][rP + 4][pc];
                aP0 = __builtin_amdgcn_mfma_f32_16x16x32_bf16(BP, A[0][ks], aP0, 0, 0, 0);
                aQ0 = __builtin_amdgcn_mfma_f32_16x16x32_bf16(BQ, A[0][ks], aQ0, 0, 0, 0);
                aP1 = __builtin_amdgcn_mfma_f32_16x16x32_bf16(BP, A[1][ks], aP1, 0, 0, 0);
                aQ1 = __builtin_amdgcn_mfma_f32_16x16x32_bf16(BQ, A[1][ks], aQ1, 0, 0, 0);
            }
            const int g0 = nt * 64 + nsp * 32 + kg * 8;
            f32x4 b0 = *(const f32x4*)(b_ih + g0);
            f32x4 b1 = *(const f32x4*)(b_ih + g0 + 4);
            long m = m0 + lr;
            if (m < N_NODES) {
                short8b pk;
#pragma unroll
                for (int i = 0; i < 4; ++i) {
                    pk[i]     = f2bf(aP0[i] + b0[i]);
                    pk[4 + i] = f2bf(aQ0[i] + b1[i]);
                }
                *(short8b*)(gi_all + m * G_DIM + g0) = pk;
            }
            m = m0 + 16 + lr;
            if (m < N_NODES) {
                short8b pk;
#pragma unroll
                for (int i = 0; i < 4; ++i) {
                    pk[i]     = f2bf(aP1[i] + b0[i]);
                    pk[4 + i] = f2bf(aQ1[i] + b1[i]);
                }
                *(short8b*)(gi_all + m * G_DIM + g0) = pk;
            }
        }
        if (nt < 11) {
            __syncthreads();
#pragma unroll
            for (int q = 0; q < 4; ++q) {
                int slot = (sp >> 1) + 2 * q;
                int pc = ((slot ^ psr) << 5) + (sp & 1) * 16;
                *(short8b*)&Bs[cur ^ 1][sr][pc]     = st[2 * q];
                *(short8b*)&Bs[cur ^ 1][sr][pc + 8] = st[2 * q + 1];
            }
            __syncthreads();
        }
    }
}

// ---------------------------------------------------------------------------
// One depth layer, v3: 512 threads / 8 waves; tile = 32 nodes x ALL 768 gate
// cols (wave wv owns cols [wv*32, wv*32+32) of each 256-col gate chunk).
// Single shared gather staging per tile (no duplication). LDS swizzle at 16B
// chunk granularity: chunk' = chunk ^ (row&7)  -> conflict-free b128 reads.
// gi loads issued early (land under MFMA). Gather-based, no atomics.
// ---------------------------------------------------------------------------
__global__ __launch_bounds__(512) void k_layer(
    const int* __restrict__ layer_nodes,
    const int* __restrict__ child_idx,
    const int* __restrict__ child_cnt,
    const int* __restrict__ Mdev,
    const int* __restrict__ layer_cnt,
    const unsigned short* __restrict__ whb,
    const unsigned short* __restrict__ gi_all,
    const float* __restrict__ b_hh,
    unsigned short* __restrict__ h_all,
    float* __restrict__ out,
    int d, int C) {
    __shared__ unsigned short Ab[32][256];   // swizzled 16B chunks
    __shared__ int Nd[32];

    const int cntd = layer_cnt[d];
    if (cntd == 0) return;
    const int M = Mdev[0];
    const int ntiles = (cntd + 31) >> 5;
    const long pbase = (long)d * M;

    const int tid = threadIdx.x;
    const int wv = tid >> 6, lane = tid & 63;
    const int lr = lane & 15, kg = lane >> 4;
    const int cb = wv * 32;                 // col base within each 256-chunk

    const int srow = tid >> 4;              // 0..31 staging row (16 thr/row)
    const int sc = tid & 15;                // 8-col chunk id within half-row

    for (int tile = blockIdx.x; tile < ntiles; tile += gridDim.x) {
        __syncthreads();   // previous tile's Ab reads done
        // ---- gather staging: h_prev = mean(children h), swizzled bf16 LDS ----
        {
            int idx = tile * 32 + srow;
            int node = (idx < cntd) ? layer_nodes[pbase + idx] : -1;
            if (sc == 0) Nd[srow] = node;
            int cc = 0;
            const int* ch = nullptr;
            if (node >= 0) {
                cc = child_cnt[pbase + idx];
                ch = child_idx + (size_t)(pbase + idx) * C;
            }
            float inv = 1.0f / (float)(cc > 0 ? cc : 1);
            float sum[16];
#pragma unroll
            for (int i = 0; i < 16; ++i) sum[i] = 0.f;
            for (int c = 0; c < cc; ++c) {
                int kid = ch[c];
                const unsigned short* hr = h_all + (size_t)kid * H_DIM + sc * 8;
                short8b v0 = *(const short8b*)hr;          // cols sc*8..+7
                short8b v1 = *(const short8b*)(hr + 128);  // cols 128+sc*8..+7
#pragma unroll
                for (int i = 0; i < 8; ++i) {
                    sum[i]     += bf2f((unsigned short)v0[i]);
                    sum[8 + i] += bf2f((unsigned short)v1[i]);
                }
            }
            short8b q0, q1;
#pragma unroll
            for (int i = 0; i < 8; ++i) {
                q0[i] = f2bf(sum[i] * inv);
                q1[i] = f2bf(sum[8 + i] * inv);
            }
            const int g = srow & 7;
            *(short8b*)&Ab[srow][(sc ^ g) << 3]        = q0;   // chunk sc
            *(short8b*)&Ab[srow][(16 + (sc ^ g)) << 3] = q1;   // chunk 16+sc
        }
        __syncthreads();

        // ---- early-issue gi loads (land under the MFMA phase) ----
        int nds[2][4];
        unsigned short g_r[2][4][2], g_z[2][4][2], g_n[2][4][2];
#pragma unroll
        for (int ms = 0; ms < 2; ++ms)
#pragma unroll
            for (int i = 0; i < 4; ++i) {
                int nd = Nd[ms * 16 + kg * 4 + i];
                nds[ms][i] = nd;
                const unsigned short* gp =
                    gi_all + (size_t)(nd >= 0 ? nd : 0) * G_DIM;
#pragma unroll
                for (int ns = 0; ns < 2; ++ns) {
                    int k = cb + ns * 16 + lr;
                    g_r[ms][i][ns] = gp[k];
                    g_z[ms][i][ns] = gp[256 + k];
                    g_n[ms][i][ns] = gp[512 + k];
                }
            }

        // ---- GEMM: acc[c][ms][ns] = h_prev @ w_hh^T (A from swizzled LDS) ----
        const f32x4 zf = {0.f, 0.f, 0.f, 0.f};
        f32x4 acc[3][2][2];
#pragma unroll
        for (int c = 0; c < 3; ++c)
#pragma unroll
            for (int ms = 0; ms < 2; ++ms)
#pragma unroll
                for (int ns = 0; ns < 2; ++ns) acc[c][ms][ns] = zf;

#pragma unroll
        for (int ks = 0; ks < 8; ++ks) {
            const int ch0 = (ks * 4 + kg) ^ (lr & 7);
            short8b A0 = *(const short8b*)&Ab[lr][ch0 << 3];
            short8b A1 = *(const short8b*)&Ab[16 + lr][ch0 << 3];
#pragma unroll
            for (int c = 0; c < 3; ++c)
#pragma unroll
                for (int ns = 0; ns < 2; ++ns) {
                    short8b B = *(const short8b*)(whb
                        + (size_t)(c * 256 + cb + ns * 16 + lr) * H_DIM
                        + ks * 32 + kg * 8);
                    acc[c][0][ns] = __builtin_amdgcn_mfma_f32_16x16x32_bf16(
                        A0, B, acc[c][0][ns], 0, 0, 0);
                    acc[c][1][ns] = __builtin_amdgcn_mfma_f32_16x16x32_bf16(
                        A1, B, acc[c][1][ns], 0, 0, 0);
                }
        }

        // ---- fused GRU epilogue ----
#pragma unroll
        for (int ms = 0; ms < 2; ++ms)
#pragma unroll
            for (int i = 0; i < 4; ++i) {
                const int rl = ms * 16 + kg * 4 + i;
                const int nd = nds[ms][i];
                if (nd < 0) continue;
#pragma unroll
                for (int ns = 0; ns < 2; ++ns) {
                    const int k = cb + ns * 16 + lr;
                    const int hp_ch = ((k >> 3) ^ (rl & 7)) & 31;
                    // note: XOR acts only within the low 3 bits of the 5-bit chunk id
                    const int hp_off = (((k >> 3) & 24) | (((k >> 3) ^ rl) & 7)) * 8 + (k & 7);
                    float hp = bf2f(Ab[rl][hp_off]);
                    (void)hp_ch;
                    float xr = bf2f(g_r[ms][i][ns]) + acc[0][ms][ns][i] + b_hh[k];
                    float xz = bf2f(g_z[ms][i][ns]) + acc[1][ms][ns][i] + b_hh[256 + k];
                    float r = 1.0f / (1.0f + expf(-xr));
                    float z = 1.0f / (1.0f + expf(-xz));
                    float n = tanhf(bf2f(g_n[ms][i][ns]) +
                                    r * (acc[2][ms][ns][i] + b_hh[512 + k]));
                    float h = (1.0f - z) * n + z * hp;
                    if (d == 0) {
                        out[(size_t)(nd / S_NODES) * H_DIM + k] = h;
                    } else {
                        h_all[(size_t)nd * H_DIM + k] = f2bf(h);
                    }
                }
            }
    }
}

// ---------------------------------------------------------------------------
extern "C" void kernel_launch(void* const* d_in, const int* in_sizes, int n_in,
                              void* d_out, int out_size, void* d_ws, size_t ws_size,
                              hipStream_t stream) {
    const float* inputs = (const float*)d_in[0];
    const float* w_ih   = (const float*)d_in[1];
    const float* w_hh   = (const float*)d_in[2];
    const float* b_ih   = (const float*)d_in[3];
    const float* b_hh   = (const float*)d_in[4];
    const int* layer_nodes = (const int*)d_in[5];
    const int* child_idx   = (const int*)d_in[6];
    const int* child_cnt   = (const int*)d_in[7];

    const int LM = in_sizes[5];
    const int C  = in_sizes[6] / in_sizes[5];

    char* w = (char*)d_ws;
    size_t o = 0;
    auto alloc = [&](size_t bytes) {
        void* p = w + o;
        o += (bytes + 255) & ~(size_t)255;
        return p;
    };
    unsigned short* wib    = (unsigned short*)alloc((size_t)G_DIM * F_DIM * 2);
    unsigned short* whb    = (unsigned short*)alloc((size_t)G_DIM * H_DIM * 2);
    unsigned short* xb     = (unsigned short*)alloc((size_t)N_NODES * F_DIM * 2);
    unsigned short* h_all  = (unsigned short*)alloc((size_t)N_NODES * H_DIM * 2);
    unsigned short* gi_all = (unsigned short*)alloc((size_t)N_NODES * G_DIM * 2);
    int*            Mdev      = (int*)alloc(4);
    int*            layer_cnt = (int*)alloc(D_MAX * 4);
    (void)ws_size;

    hipMemsetAsync(Mdev, 0x7F, 4, stream);                 // 0x7F7F7F7F > LM
    hipMemsetAsync(layer_cnt, 0, D_MAX * 4, stream);

    k_zero<<<2048, 256, 0, stream>>>((float4*)h_all, N_NODES * H_DIM * 2 / 16);
    k_convx<<<2048, 256, 0, stream>>>(inputs, xb, N_NODES * F_DIM / 8);
    k_findM<<<256, 256, 0, stream>>>(layer_nodes, LM, Mdev);
    k_hist<<<256, 256, 0, stream>>>(layer_nodes, Mdev, layer_cnt, LM);
    k_convw<<<(G_DIM * F_DIM + 255) / 256, 256, 0, stream>>>(w_ih, w_hh, wib, whb);

    // One-shot feed-forward GEMM (b_ih folded in)
    k_gemm_x<<<(N_NODES + 127) / 128, 256, 0, stream>>>(xb, wib, b_ih, gi_all);

    // Depth layers, deepest first (empty layers exit immediately)
    for (int d = D_MAX - 1; d >= 0; --d)
        k_layer<<<2048, 512, 0, stream>>>(layer_nodes, child_idx, child_cnt,
                                          Mdev, layer_cnt, whb, gi_all, b_hh,
                                          h_all, (float*)d_out, d, C);
}

// Round 10
// 1452.739 us; speedup vs baseline: 1.0658x; 1.0658x over previous
//
#include <hip/hip_runtime.h>
#include <hip/hip_bf16.h>
#include <math.h>

#define N_NODES 200000
#define T_TREES 2000
#define S_NODES 100
#define F_DIM 256
#define H_DIM 256
#define G_DIM 768   // 3*H
#define D_MAX 28    // upper bound on depth layers (actual ~16)

typedef __attribute__((ext_vector_type(8))) short short8b;   // 8 bf16 = 4 VGPR
typedef __attribute__((ext_vector_type(4))) float f32x4;

static __device__ __forceinline__ unsigned short f2bf(float x) {
    union { __hip_bfloat16 h; unsigned short u; } cv;
    cv.h = __float2bfloat16(x);
    return cv.u;
}
static __device__ __forceinline__ float bf2f(unsigned short u) {
    return __uint_as_float(((unsigned)u) << 16);
}

// ---------------------------------------------------------------------------
__global__ void k_zero(float4* __restrict__ p, int n4) {
    float4 z = make_float4(0.f, 0.f, 0.f, 0.f);
    for (int i = blockIdx.x * blockDim.x + threadIdx.x; i < n4;
         i += gridDim.x * blockDim.x)
        p[i] = z;
}

// x (fp32) -> bf16, 8 elems/thread
__global__ void k_convx(const float* __restrict__ x, unsigned short* __restrict__ xb,
                        int n8) {
    for (int i = blockIdx.x * blockDim.x + threadIdx.x; i < n8;
         i += gridDim.x * blockDim.x) {
        const float4* px = (const float4*)(x + (size_t)i * 8);
        float4 u = px[0], v = px[1];
        short8b t;
        t[0] = f2bf(u.x); t[1] = f2bf(u.y); t[2] = f2bf(u.z); t[3] = f2bf(u.w);
        t[4] = f2bf(v.x); t[5] = f2bf(v.y); t[6] = f2bf(v.z); t[7] = f2bf(v.w);
        *(short8b*)(xb + (size_t)i * 8) = t;
    }
}

// M = min{ p >= T : layer_nodes[p] < N } (layer 0 is exactly the T roots)
__global__ void k_findM(const int* __restrict__ ln, int LM, int* __restrict__ Mdev) {
    int local = 0x7F7F7F7F;
    for (int p = T_TREES + blockIdx.x * blockDim.x + threadIdx.x; p < LM;
         p += gridDim.x * blockDim.x)
        if (ln[p] < N_NODES && p < local) local = p;
#pragma unroll
    for (int off = 32; off; off >>= 1) {
        int o = __shfl_down(local, off);
        if (o < local) local = o;
    }
    __shared__ int wmin[4];
    if ((threadIdx.x & 63) == 0) wmin[threadIdx.x >> 6] = local;
    __syncthreads();
    if (threadIdx.x == 0) {
        int m = wmin[0];
        for (int i = 1; i < 4; ++i) if (wmin[i] < m) m = wmin[i];
        if (m < 0x7F7F7F7F) atomicMin(Mdev, m);
    }
}

// layer_cnt[d] = #valid nodes in layer d (valid entries are a row prefix)
__global__ void k_hist(const int* __restrict__ ln, const int* __restrict__ Mdev,
                       int* __restrict__ layer_cnt, int LM) {
    __shared__ int h[D_MAX];
    if (threadIdx.x < D_MAX) h[threadIdx.x] = 0;
    __syncthreads();
    const int M = Mdev[0];
    for (int p = blockIdx.x * blockDim.x + threadIdx.x; p < LM;
         p += gridDim.x * blockDim.x)
        if (ln[p] < N_NODES) {
            int d = p / M;
            if (d < D_MAX) atomicAdd(&h[d], 1);
        }
    __syncthreads();
    if (threadIdx.x < D_MAX && h[threadIdx.x])
        atomicAdd(&layer_cnt[threadIdx.x], h[threadIdx.x]);
}

// Weights fp32 -> bf16 (row-major [g][k])
__global__ void k_convw(const float* __restrict__ wi, const float* __restrict__ wh,
                        unsigned short* __restrict__ wib, unsigned short* __restrict__ whb) {
    int i = blockIdx.x * blockDim.x + threadIdx.x;
    if (i < G_DIM * F_DIM) {
        wib[i] = f2bf(wi[i]);
        whb[i] = f2bf(wh[i]);
    }
}

// ---------------------------------------------------------------------------
// One-shot GEMM (unchanged from round 8): gi_all[m][g] = xb@w_ih^T + b_ih (bf16)
// ---------------------------------------------------------------------------
__global__ __launch_bounds__(256) void k_gemm_x(
    const unsigned short* __restrict__ xb,
    const unsigned short* __restrict__ wib,
    const float* __restrict__ b_ih,
    unsigned short* __restrict__ gi_all) {
    __shared__ unsigned short Bs[2][64][256];

    const int tid = threadIdx.x;
    const int wv = tid >> 6, lane = tid & 63;
    const int lr = lane & 15, kg = lane >> 4;
    const long m0 = (long)blockIdx.x * 128 + wv * 32;

    short8b A[2][8];
#pragma unroll
    for (int ms = 0; ms < 2; ++ms) {
        long r = m0 + ms * 16 + lr;
        if (r > N_NODES - 1) r = N_NODES - 1;
        const unsigned short* xp = xb + r * F_DIM + kg * 8;
#pragma unroll
        for (int ks = 0; ks < 8; ++ks)
            A[ms][ks] = *(const short8b*)(xp + ks * 32);
    }

    const int sr = tid >> 2, sp = tid & 3;
    const int psr = (sr >> 3) & 1;
    const int gp_off = (lr >> 2) * 8 + (lr & 3);
    const int prow = (gp_off >> 3) & 1;

    short8b st[8];
    {
        const unsigned short* src = wib + (size_t)sr * F_DIM;
#pragma unroll
        for (int q = 0; q < 4; ++q) {
            int c = sp * 16 + q * 64;
            st[2 * q]     = *(const short8b*)(src + c);
            st[2 * q + 1] = *(const short8b*)(src + c + 8);
        }
#pragma unroll
        for (int q = 0; q < 4; ++q) {
            int slot = (sp >> 1) + 2 * q;
            int pc = ((slot ^ psr) << 5) + (sp & 1) * 16;
            *(short8b*)&Bs[0][sr][pc]     = st[2 * q];
            *(short8b*)&Bs[0][sr][pc + 8] = st[2 * q + 1];
        }
    }
    __syncthreads();

    const f32x4 zf = {0.f, 0.f, 0.f, 0.f};

    for (int nt = 0; nt < 12; ++nt) {
        const int cur = nt & 1;
        if (nt < 11) {
            const unsigned short* src = wib + (size_t)((nt + 1) * 64 + sr) * F_DIM;
#pragma unroll
            for (int q = 0; q < 4; ++q) {
                int c = sp * 16 + q * 64;
                st[2 * q]     = *(const short8b*)(src + c);
                st[2 * q + 1] = *(const short8b*)(src + c + 8);
            }
        }
#pragma unroll
        for (int nsp = 0; nsp < 2; ++nsp) {
            f32x4 aP0 = zf, aQ0 = zf, aP1 = zf, aQ1 = zf;
            const int rP = nsp * 32 + gp_off;
#pragma unroll
            for (int ks = 0; ks < 8; ++ks) {
                const int pc = ((ks ^ prow) << 5) + kg * 8;
                short8b BP = *(const short8b*)&Bs[cur][rP][pc];
                short8b BQ = *(const short8b*)&Bs[cur][rP + 4][pc];
                aP0 = __builtin_amdgcn_mfma_f32_16x16x32_bf16(BP, A[0][ks], aP0, 0, 0, 0);
                aQ0 = __builtin_amdgcn_mfma_f32_16x16x32_bf16(BQ, A[0][ks], aQ0, 0, 0, 0);
                aP1 = __builtin_amdgcn_mfma_f32_16x16x32_bf16(BP, A[1][ks], aP1, 0, 0, 0);
                aQ1 = __builtin_amdgcn_mfma_f32_16x16x32_bf16(BQ, A[1][ks], aQ1, 0, 0, 0);
            }
            const int g0 = nt * 64 + nsp * 32 + kg * 8;
            f32x4 b0 = *(const f32x4*)(b_ih + g0);
            f32x4 b1 = *(const f32x4*)(b_ih + g0 + 4);
            long m = m0 + lr;
            if (m < N_NODES) {
                short8b pk;
#pragma unroll
                for (int i = 0; i < 4; ++i) {
                    pk[i]     = f2bf(aP0[i] + b0[i]);
                    pk[4 + i] = f2bf(aQ0[i] + b1[i]);
                }
                *(short8b*)(gi_all + m * G_DIM + g0) = pk;
            }
            m = m0 + 16 + lr;
            if (m < N_NODES) {
                short8b pk;
#pragma unroll
                for (int i = 0; i < 4; ++i) {
                    pk[i]     = f2bf(aP1[i] + b0[i]);
                    pk[4 + i] = f2bf(aQ1[i] + b1[i]);
                }
                *(short8b*)(gi_all + m * G_DIM + g0) = pk;
            }
        }
        if (nt < 11) {
            __syncthreads();
#pragma unroll
            for (int q = 0; q < 4; ++q) {
                int slot = (sp >> 1) + 2 * q;
                int pc = ((slot ^ psr) << 5) + (sp & 1) * 16;
                *(short8b*)&Bs[cur ^ 1][sr][pc]     = st[2 * q];
                *(short8b*)&Bs[cur ^ 1][sr][pc + 8] = st[2 * q + 1];
            }
            __syncthreads();
        }
    }
}

// ---------------------------------------------------------------------------
// One depth layer, v4: 512 thr / 8 waves; tile = 32 nodes x all 768 cols.
// Staging phase now ALSO copies the tile's 32 gi rows into LDS with coalesced
// 16B loads (kills the 2B-scattered gi reads AND the r9 register spill).
// Ab keeps the 16B-chunk XOR swizzle (chunk' = chunk ^ (row&7)).
// ---------------------------------------------------------------------------
__global__ __launch_bounds__(512) void k_layer(
    const int* __restrict__ layer_nodes,
    const int* __restrict__ child_idx,
    const int* __restrict__ child_cnt,
    const int* __restrict__ Mdev,
    const int* __restrict__ layer_cnt,
    const unsigned short* __restrict__ whb,
    const unsigned short* __restrict__ gi_all,
    const float* __restrict__ b_hh,
    unsigned short* __restrict__ h_all,
    float* __restrict__ out,
    int d, int C) {
    __shared__ unsigned short Ab[32][256];   // swizzled h_prev (16B chunks)
    __shared__ unsigned short Ag[32][776];   // gi rows (pitch 776 = 4 mod 32 dw)
    __shared__ int Nd[32];

    const int cntd = layer_cnt[d];
    if (cntd == 0) return;
    const int M = Mdev[0];
    const int ntiles = (cntd + 31) >> 5;
    const long pbase = (long)d * M;

    const int tid = threadIdx.x;
    const int wv = tid >> 6, lane = tid & 63;
    const int lr = lane & 15, kg = lane >> 4;
    const int cb = wv * 32;                 // col base within each 256-chunk

    float bh[3][2];
#pragma unroll
    for (int c = 0; c < 3; ++c)
#pragma unroll
        for (int ns = 0; ns < 2; ++ns)
            bh[c][ns] = b_hh[c * 256 + cb + ns * 16 + lr];

    const int srow = tid >> 4;              // 0..31 staging row (16 thr/row)
    const int sc = tid & 15;

    for (int tile = blockIdx.x; tile < ntiles; tile += gridDim.x) {
        __syncthreads();   // previous tile's LDS reads done
        // ---- staging: gather h_prev AND copy gi row to LDS ----
        {
            int idx = tile * 32 + srow;
            int node = (idx < cntd) ? layer_nodes[pbase + idx] : -1;
            if (sc == 0) Nd[srow] = node;
            // gi row copy: 16 thr x 96B, coalesced 256B bursts
            {
                const unsigned short* gp =
                    gi_all + (size_t)(node >= 0 ? node : 0) * G_DIM;
#pragma unroll
                for (int pass = 0; pass < 6; ++pass) {
                    int col = sc * 8 + pass * 128;
                    *(short8b*)&Ag[srow][col] = *(const short8b*)(gp + col);
                }
            }
            // gather: h_prev = mean(children h); thread owns cols sc*16..+15
            int cc = 0;
            const int* ch = nullptr;
            if (node >= 0) {
                cc = child_cnt[pbase + idx];
                ch = child_idx + (size_t)(pbase + idx) * C;
            }
            float inv = 1.0f / (float)(cc > 0 ? cc : 1);
            float sum[16];
#pragma unroll
            for (int i = 0; i < 16; ++i) sum[i] = 0.f;
            for (int c = 0; c < cc; ++c) {
                int kid = ch[c];
                const unsigned short* hr = h_all + (size_t)kid * H_DIM + sc * 16;
                short8b v0 = *(const short8b*)hr;
                short8b v1 = *(const short8b*)(hr + 8);
#pragma unroll
                for (int i = 0; i < 8; ++i) {
                    sum[i]     += bf2f((unsigned short)v0[i]);
                    sum[8 + i] += bf2f((unsigned short)v1[i]);
                }
            }
            short8b q0, q1;
#pragma unroll
            for (int i = 0; i < 8; ++i) {
                q0[i] = f2bf(sum[i] * inv);
                q1[i] = f2bf(sum[8 + i] * inv);
            }
            const int g = srow & 7;
            const int c0 = 2 * sc, c1 = 2 * sc + 1;   // 16B chunk ids
            *(short8b*)&Ab[srow][((c0 & 24) | ((c0 ^ g) & 7)) << 3] = q0;
            *(short8b*)&Ab[srow][((c1 & 24) | ((c1 ^ g) & 7)) << 3] = q1;
        }
        __syncthreads();

        // ---- GEMM: acc[c][ms][ns] = h_prev @ w_hh^T (A from swizzled LDS) ----
        const f32x4 zf = {0.f, 0.f, 0.f, 0.f};
        f32x4 acc[3][2][2];
#pragma unroll
        for (int c = 0; c < 3; ++c)
#pragma unroll
            for (int ms = 0; ms < 2; ++ms)
#pragma unroll
                for (int ns = 0; ns < 2; ++ns) acc[c][ms][ns] = zf;

#pragma unroll
        for (int ks = 0; ks < 8; ++ks) {
            const int cch = ks * 4 + kg;
            const int pc = (((cch & 24) | ((cch ^ lr) & 7))) << 3;
            short8b A0 = *(const short8b*)&Ab[lr][pc];
            short8b A1 = *(const short8b*)&Ab[16 + lr][pc];
#pragma unroll
            for (int c = 0; c < 3; ++c)
#pragma unroll
                for (int ns = 0; ns < 2; ++ns) {
                    short8b B = *(const short8b*)(whb
                        + (size_t)(c * 256 + cb + ns * 16 + lr) * H_DIM
                        + ks * 32 + kg * 8);
                    acc[c][0][ns] = __builtin_amdgcn_mfma_f32_16x16x32_bf16(
                        A0, B, acc[c][0][ns], 0, 0, 0);
                    acc[c][1][ns] = __builtin_amdgcn_mfma_f32_16x16x32_bf16(
                        A1, B, acc[c][1][ns], 0, 0, 0);
                }
        }

        // ---- fused GRU epilogue (gi from LDS) ----
#pragma unroll
        for (int ms = 0; ms < 2; ++ms)
#pragma unroll
            for (int i = 0; i < 4; ++i) {
                const int rl = ms * 16 + kg * 4 + i;
                const int nd = Nd[rl];
                if (nd < 0) continue;
#pragma unroll
                for (int ns = 0; ns < 2; ++ns) {
                    const int k = cb + ns * 16 + lr;
                    const int kc = k >> 3;
                    const int hp_off = (((kc & 24) | ((kc ^ rl) & 7)) << 3) + (k & 7);
                    float hp = bf2f(Ab[rl][hp_off]);
                    float xr = bf2f(Ag[rl][k])       + acc[0][ms][ns][i] + bh[0][ns];
                    float xz = bf2f(Ag[rl][256 + k]) + acc[1][ms][ns][i] + bh[1][ns];
                    float r = 1.0f / (1.0f + expf(-xr));
                    float z = 1.0f / (1.0f + expf(-xz));
                    float n = tanhf(bf2f(Ag[rl][512 + k]) +
                                    r * (acc[2][ms][ns][i] + bh[2][ns]));
                    float h = (1.0f - z) * n + z * hp;
                    if (d == 0) {
                        out[(size_t)(nd / S_NODES) * H_DIM + k] = h;
                    } else {
                        h_all[(size_t)nd * H_DIM + k] = f2bf(h);
                    }
                }
            }
    }
}

// ---------------------------------------------------------------------------
extern "C" void kernel_launch(void* const* d_in, const int* in_sizes, int n_in,
                              void* d_out, int out_size, void* d_ws, size_t ws_size,
                              hipStream_t stream) {
    const float* inputs = (const float*)d_in[0];
    const float* w_ih   = (const float*)d_in[1];
    const float* w_hh   = (const float*)d_in[2];
    const float* b_ih   = (const float*)d_in[3];
    const float* b_hh   = (const float*)d_in[4];
    const int* layer_nodes = (const int*)d_in[5];
    const int* child_idx   = (const int*)d_in[6];
    const int* child_cnt   = (const int*)d_in[7];

    const int LM = in_sizes[5];
    const int C  = in_sizes[6] / in_sizes[5];

    char* w = (char*)d_ws;
    size_t o = 0;
    auto alloc = [&](size_t bytes) {
        void* p = w + o;
        o += (bytes + 255) & ~(size_t)255;
        return p;
    };
    unsigned short* wib    = (unsigned short*)alloc((size_t)G_DIM * F_DIM * 2);
    unsigned short* whb    = (unsigned short*)alloc((size_t)G_DIM * H_DIM * 2);
    unsigned short* xb     = (unsigned short*)alloc((size_t)N_NODES * F_DIM * 2);
    unsigned short* h_all  = (unsigned short*)alloc((size_t)N_NODES * H_DIM * 2);
    unsigned short* gi_all = (unsigned short*)alloc((size_t)N_NODES * G_DIM * 2);
    int*            Mdev      = (int*)alloc(4);
    int*            layer_cnt = (int*)alloc(D_MAX * 4);
    (void)ws_size;

    hipMemsetAsync(Mdev, 0x7F, 4, stream);                 // 0x7F7F7F7F > LM
    hipMemsetAsync(layer_cnt, 0, D_MAX * 4, stream);

    k_zero<<<2048, 256, 0, stream>>>((float4*)h_all, N_NODES * H_DIM * 2 / 16);
    k_convx<<<2048, 256, 0, stream>>>(inputs, xb, N_NODES * F_DIM / 8);
    k_findM<<<256, 256, 0, stream>>>(layer_nodes, LM, Mdev);
    k_hist<<<256, 256, 0, stream>>>(layer_nodes, Mdev, layer_cnt, LM);
    k_convw<<<(G_DIM * F_DIM + 255) / 256, 256, 0, stream>>>(w_ih, w_hh, wib, whb);

    // One-shot feed-forward GEMM (b_ih folded in)
    k_gemm_x<<<(N_NODES + 127) / 128, 256, 0, stream>>>(xb, wib, b_ih, gi_all);

    // Depth layers, deepest first (empty layers exit immediately)
    for (int d = D_MAX - 1; d >= 0; --d)
        k_layer<<<2048, 512, 0, stream>>>(layer_nodes, child_idx, child_cnt,
                                          Mdev, layer_cnt, whb, gi_all, b_hh,
                                          h_all, (float*)d_out, d, C);
}

// Round 11
// 1041.413 us; speedup vs baseline: 1.4868x; 1.3950x over previous
//
#include <hip/hip_runtime.h>
#include <hip/hip_bf16.h>
#include <math.h>

#define N_NODES 200000
#define T_TREES 2000
#define S_NODES 100
#define F_DIM 256
#define H_DIM 256
#define G_DIM 768   // 3*H
#define D_MAX 28    // upper bound on depth layers (actual ~16)

typedef __attribute__((ext_vector_type(8))) short short8b;   // 8 bf16 = 4 VGPR
typedef __attribute__((ext_vector_type(4))) float f32x4;

static __device__ __forceinline__ unsigned short f2bf(float x) {
    union { __hip_bfloat16 h; unsigned short u; } cv;
    cv.h = __float2bfloat16(x);
    return cv.u;
}
static __device__ __forceinline__ float bf2f(unsigned short u) {
    return __uint_as_float(((unsigned)u) << 16);
}
// fast sigmoid/tanh via v_exp_f32 + v_rcp_f32 (overflow-safe forms)
static __device__ __forceinline__ float fsig(float x) {
    return __builtin_amdgcn_rcpf(1.0f + __expf(-x));
}
static __device__ __forceinline__ float ftanh(float x) {
    return 1.0f - 2.0f * __builtin_amdgcn_rcpf(__expf(2.0f * x) + 1.0f);
}

// ---------------------------------------------------------------------------
__global__ void k_zero(float4* __restrict__ p, int n4) {
    float4 z = make_float4(0.f, 0.f, 0.f, 0.f);
    for (int i = blockIdx.x * blockDim.x + threadIdx.x; i < n4;
         i += gridDim.x * blockDim.x)
        p[i] = z;
}

// x (fp32) -> bf16, 8 elems/thread
__global__ void k_convx(const float* __restrict__ x, unsigned short* __restrict__ xb,
                        int n8) {
    for (int i = blockIdx.x * blockDim.x + threadIdx.x; i < n8;
         i += gridDim.x * blockDim.x) {
        const float4* px = (const float4*)(x + (size_t)i * 8);
        float4 u = px[0], v = px[1];
        short8b t;
        t[0] = f2bf(u.x); t[1] = f2bf(u.y); t[2] = f2bf(u.z); t[3] = f2bf(u.w);
        t[4] = f2bf(v.x); t[5] = f2bf(v.y); t[6] = f2bf(v.z); t[7] = f2bf(v.w);
        *(short8b*)(xb + (size_t)i * 8) = t;
    }
}

// M = min{ p >= T : layer_nodes[p] < N } (layer 0 is exactly the T roots)
__global__ void k_findM(const int* __restrict__ ln, int LM, int* __restrict__ Mdev) {
    int local = 0x7F7F7F7F;
    for (int p = T_TREES + blockIdx.x * blockDim.x + threadIdx.x; p < LM;
         p += gridDim.x * blockDim.x)
        if (ln[p] < N_NODES && p < local) local = p;
#pragma unroll
    for (int off = 32; off; off >>= 1) {
        int o = __shfl_down(local, off);
        if (o < local) local = o;
    }
    __shared__ int wmin[4];
    if ((threadIdx.x & 63) == 0) wmin[threadIdx.x >> 6] = local;
    __syncthreads();
    if (threadIdx.x == 0) {
        int m = wmin[0];
        for (int i = 1; i < 4; ++i) if (wmin[i] < m) m = wmin[i];
        if (m < 0x7F7F7F7F) atomicMin(Mdev, m);
    }
}

// layer_cnt[d] = #valid nodes in layer d (valid entries are a row prefix)
__global__ void k_hist(const int* __restrict__ ln, const int* __restrict__ Mdev,
                       int* __restrict__ layer_cnt, int LM) {
    __shared__ int h[D_MAX];
    if (threadIdx.x < D_MAX) h[threadIdx.x] = 0;
    __syncthreads();
    const int M = Mdev[0];
    for (int p = blockIdx.x * blockDim.x + threadIdx.x; p < LM;
         p += gridDim.x * blockDim.x)
        if (ln[p] < N_NODES) {
            int d = p / M;
            if (d < D_MAX) atomicAdd(&h[d], 1);
        }
    __syncthreads();
    if (threadIdx.x < D_MAX && h[threadIdx.x])
        atomicAdd(&layer_cnt[threadIdx.x], h[threadIdx.x]);
}

// Weights fp32 -> bf16 (row-major [g][k])
__global__ void k_convw(const float* __restrict__ wi, const float* __restrict__ wh,
                        unsigned short* __restrict__ wib, unsigned short* __restrict__ whb) {
    int i = blockIdx.x * blockDim.x + threadIdx.x;
    if (i < G_DIM * F_DIM) {
        wib[i] = f2bf(wi[i]);
        whb[i] = f2bf(wh[i]);
    }
}

// ---------------------------------------------------------------------------
// One-shot GEMM (unchanged from round 8): gi_all[m][g] = xb@w_ih^T + b_ih (bf16)
// ---------------------------------------------------------------------------
__global__ __launch_bounds__(256) void k_gemm_x(
    const unsigned short* __restrict__ xb,
    const unsigned short* __restrict__ wib,
    const float* __restrict__ b_ih,
    unsigned short* __restrict__ gi_all) {
    __shared__ unsigned short Bs[2][64][256];

    const int tid = threadIdx.x;
    const int wv = tid >> 6, lane = tid & 63;
    const int lr = lane & 15, kg = lane >> 4;
    const long m0 = (long)blockIdx.x * 128 + wv * 32;

    short8b A[2][8];
#pragma unroll
    for (int ms = 0; ms < 2; ++ms) {
        long r = m0 + ms * 16 + lr;
        if (r > N_NODES - 1) r = N_NODES - 1;
        const unsigned short* xp = xb + r * F_DIM + kg * 8;
#pragma unroll
        for (int ks = 0; ks < 8; ++ks)
            A[ms][ks] = *(const short8b*)(xp + ks * 32);
    }

    const int sr = tid >> 2, sp = tid & 3;
    const int psr = (sr >> 3) & 1;
    const int gp_off = (lr >> 2) * 8 + (lr & 3);
    const int prow = (gp_off >> 3) & 1;

    short8b st[8];
    {
        const unsigned short* src = wib + (size_t)sr * F_DIM;
#pragma unroll
        for (int q = 0; q < 4; ++q) {
            int c = sp * 16 + q * 64;
            st[2 * q]     = *(const short8b*)(src + c);
            st[2 * q + 1] = *(const short8b*)(src + c + 8);
        }
#pragma unroll
        for (int q = 0; q < 4; ++q) {
            int slot = (sp >> 1) + 2 * q;
            int pc = ((slot ^ psr) << 5) + (sp & 1) * 16;
            *(short8b*)&Bs[0][sr][pc]     = st[2 * q];
            *(short8b*)&Bs[0][sr][pc + 8] = st[2 * q + 1];
        }
    }
    __syncthreads();

    const f32x4 zf = {0.f, 0.f, 0.f, 0.f};

    for (int nt = 0; nt < 12; ++nt) {
        const int cur = nt & 1;
        if (nt < 11) {
            const unsigned short* src = wib + (size_t)((nt + 1) * 64 + sr) * F_DIM;
#pragma unroll
            for (int q = 0; q < 4; ++q) {
                int c = sp * 16 + q * 64;
                st[2 * q]     = *(const short8b*)(src + c);
                st[2 * q + 1] = *(const short8b*)(src + c + 8);
            }
        }
#pragma unroll
        for (int nsp = 0; nsp < 2; ++nsp) {
            f32x4 aP0 = zf, aQ0 = zf, aP1 = zf, aQ1 = zf;
            const int rP = nsp * 32 + gp_off;
#pragma unroll
            for (int ks = 0; ks < 8; ++ks) {
                const int pc = ((ks ^ prow) << 5) + kg * 8;
                short8b BP = *(const short8b*)&Bs[cur][rP][pc];
                short8b BQ = *(const short8b*)&Bs[cur][rP + 4][pc];
                aP0 = __builtin_amdgcn_mfma_f32_16x16x32_bf16(BP, A[0][ks], aP0, 0, 0, 0);
                aQ0 = __builtin_amdgcn_mfma_f32_16x16x32_bf16(BQ, A[0][ks], aQ0, 0, 0, 0);
                aP1 = __builtin_amdgcn_mfma_f32_16x16x32_bf16(BP, A[1][ks], aP1, 0, 0, 0);
                aQ1 = __builtin_amdgcn_mfma_f32_16x16x32_bf16(BQ, A[1][ks], aQ1, 0, 0, 0);
            }
            const int g0 = nt * 64 + nsp * 32 + kg * 8;
            f32x4 b0 = *(const f32x4*)(b_ih + g0);
            f32x4 b1 = *(const f32x4*)(b_ih + g0 + 4);
            long m = m0 + lr;
            if (m < N_NODES) {
                short8b pk;
#pragma unroll
                for (int i = 0; i < 4; ++i) {
                    pk[i]     = f2bf(aP0[i] + b0[i]);
                    pk[4 + i] = f2bf(aQ0[i] + b1[i]);
                }
                *(short8b*)(gi_all + m * G_DIM + g0) = pk;
            }
            m = m0 + 16 + lr;
            if (m < N_NODES) {
                short8b pk;
#pragma unroll
                for (int i = 0; i < 4; ++i) {
                    pk[i]     = f2bf(aP1[i] + b0[i]);
                    pk[4 + i] = f2bf(aQ1[i] + b1[i]);
                }
                *(short8b*)(gi_all + m * G_DIM + g0) = pk;
            }
        }
        if (nt < 11) {
            __syncthreads();
#pragma unroll
            for (int q = 0; q < 4; ++q) {
                int slot = (sp >> 1) + 2 * q;
                int pc = ((slot ^ psr) << 5) + (sp & 1) * 16;
                *(short8b*)&Bs[cur ^ 1][sr][pc]     = st[2 * q];
                *(short8b*)&Bs[cur ^ 1][sr][pc + 8] = st[2 * q + 1];
            }
            __syncthreads();
        }
    }
}

// ---------------------------------------------------------------------------
// One depth layer, v5: 512 thr / 8 waves / __launch_bounds__(512,2) (VGPR<=256,
// no spill). grid=512 (2 blocks/CU); each block loops ~3 tiles so the r,z-gate
// whb fragments (128 VGPR) stay REGISTER-PERSISTENT across tiles; the n-gate
// streams in 4 quarter-buffers pipelined between MFMA phases. gi rows staged
// to LDS coalesced. Fast exp/tanh in the epilogue.
// ---------------------------------------------------------------------------
#define LOADC2(buf, ns_, kh_)                                                  \
  _Pragma("unroll")                                                            \
  for (int kk = 0; kk < 4; ++kk)                                               \
    buf[kk] = *(const short8b*)(whb +                                          \
        (size_t)(512 + cb + (ns_) * 16 + lr) * H_DIM + ((kh_) * 4 + kk) * 32 + kg * 8);

#define MMACP(c_)                                                              \
  _Pragma("unroll")                                                            \
  for (int ks = 0; ks < 8; ++ks) {                                             \
    const int cch = ks * 4 + kg;                                               \
    const int pc = ((cch & 24) | ((cch ^ lr) & 7)) << 3;                       \
    short8b A0 = *(const short8b*)&Ab[lr][pc];                                 \
    short8b A1 = *(const short8b*)&Ab[16 + lr][pc];                            \
    _Pragma("unroll")                                                          \
    for (int ns = 0; ns < 2; ++ns) {                                           \
      acc[c_][0][ns] = __builtin_amdgcn_mfma_f32_16x16x32_bf16(                \
          A0, Bp[c_][ns][ks], acc[c_][0][ns], 0, 0, 0);                        \
      acc[c_][1][ns] = __builtin_amdgcn_mfma_f32_16x16x32_bf16(                \
          A1, Bp[c_][ns][ks], acc[c_][1][ns], 0, 0, 0);                        \
    }                                                                          \
  }

#define MMAC2(buf, ns_, kh_)                                                   \
  _Pragma("unroll")                                                            \
  for (int kk = 0; kk < 4; ++kk) {                                             \
    const int ks = (kh_) * 4 + kk;                                             \
    const int cch = ks * 4 + kg;                                               \
    const int pc = ((cch & 24) | ((cch ^ lr) & 7)) << 3;                       \
    short8b A0 = *(const short8b*)&Ab[lr][pc];                                 \
    short8b A1 = *(const short8b*)&Ab[16 + lr][pc];                            \
    acc[2][0][ns_] = __builtin_amdgcn_mfma_f32_16x16x32_bf16(                  \
        A0, buf[kk], acc[2][0][ns_], 0, 0, 0);                                 \
    acc[2][1][ns_] = __builtin_amdgcn_mfma_f32_16x16x32_bf16(                  \
        A1, buf[kk], acc[2][1][ns_], 0, 0, 0);                                 \
  }

__global__ __launch_bounds__(512, 2) void k_layer(
    const int* __restrict__ layer_nodes,
    const int* __restrict__ child_idx,
    const int* __restrict__ child_cnt,
    const int* __restrict__ Mdev,
    const int* __restrict__ layer_cnt,
    const unsigned short* __restrict__ whb,
    const unsigned short* __restrict__ gi_all,
    const float* __restrict__ b_hh,
    unsigned short* __restrict__ h_all,
    float* __restrict__ out,
    int d, int C) {
    __shared__ unsigned short Ab[32][256];   // swizzled h_prev (16B chunks)
    __shared__ unsigned short Ag[32][776];   // gi rows (pitch 776 = 4 mod 32 dw)
    __shared__ int Nd[32];

    const int cntd = layer_cnt[d];
    if (cntd == 0) return;
    const int M = Mdev[0];
    const int ntiles = (cntd + 31) >> 5;
    if (blockIdx.x >= ntiles) return;
    const long pbase = (long)d * M;

    const int tid = threadIdx.x;
    const int wv = tid >> 6, lane = tid & 63;
    const int lr = lane & 15, kg = lane >> 4;
    const int cb = wv * 32;                 // col base within each 256-chunk

    // ---- persistent B fragments for gates r,z (c=0,1): loaded ONCE ----
    short8b Bp[2][2][8];
#pragma unroll
    for (int c = 0; c < 2; ++c)
#pragma unroll
        for (int ns = 0; ns < 2; ++ns) {
            const unsigned short* bp =
                whb + (size_t)(c * 256 + cb + ns * 16 + lr) * H_DIM + kg * 8;
#pragma unroll
            for (int ks = 0; ks < 8; ++ks)
                Bp[c][ns][ks] = *(const short8b*)(bp + ks * 32);
        }

    float bh[3][2];
#pragma unroll
    for (int c = 0; c < 3; ++c)
#pragma unroll
        for (int ns = 0; ns < 2; ++ns)
            bh[c][ns] = b_hh[c * 256 + cb + ns * 16 + lr];

    const int srow = tid >> 4;              // 0..31 staging row (16 thr/row)
    const int sc = tid & 15;

    for (int tile = blockIdx.x; tile < ntiles; tile += gridDim.x) {
        __syncthreads();   // previous tile's LDS reads done
        // ---- staging: copy gi row + gather h_prev ----
        {
            int idx = tile * 32 + srow;
            int node = (idx < cntd) ? layer_nodes[pbase + idx] : -1;
            if (sc == 0) Nd[srow] = node;
            {
                const unsigned short* gp =
                    gi_all + (size_t)(node >= 0 ? node : 0) * G_DIM;
#pragma unroll
                for (int pass = 0; pass < 6; ++pass) {
                    int col = sc * 8 + pass * 128;
                    *(short8b*)&Ag[srow][col] = *(const short8b*)(gp + col);
                }
            }
            int cc = 0;
            const int* ch = nullptr;
            if (node >= 0) {
                cc = child_cnt[pbase + idx];
                ch = child_idx + (size_t)(pbase + idx) * C;
            }
            float inv = 1.0f / (float)(cc > 0 ? cc : 1);
            float sum[16];
#pragma unroll
            for (int i = 0; i < 16; ++i) sum[i] = 0.f;
            for (int c = 0; c < cc; ++c) {
                int kid = ch[c];
                const unsigned short* hr = h_all + (size_t)kid * H_DIM + sc * 16;
                short8b v0 = *(const short8b*)hr;
                short8b v1 = *(const short8b*)(hr + 8);
#pragma unroll
                for (int i = 0; i < 8; ++i) {
                    sum[i]     += bf2f((unsigned short)v0[i]);
                    sum[8 + i] += bf2f((unsigned short)v1[i]);
                }
            }
            short8b q0, q1;
#pragma unroll
            for (int i = 0; i < 8; ++i) {
                q0[i] = f2bf(sum[i] * inv);
                q1[i] = f2bf(sum[8 + i] * inv);
            }
            const int g = srow & 7;
            const int c0 = 2 * sc, c1 = 2 * sc + 1;   // 16B chunk ids
            *(short8b*)&Ab[srow][((c0 & 24) | ((c0 ^ g) & 7)) << 3] = q0;
            *(short8b*)&Ab[srow][((c1 & 24) | ((c1 ^ g) & 7)) << 3] = q1;
        }
        __syncthreads();

        // ---- GEMM: persistent r,z + quarter-streamed n gate ----
        const f32x4 zf = {0.f, 0.f, 0.f, 0.f};
        f32x4 acc[3][2][2];
#pragma unroll
        for (int c = 0; c < 3; ++c)
#pragma unroll
            for (int ms = 0; ms < 2; ++ms)
#pragma unroll
                for (int ns = 0; ns < 2; ++ns) acc[c][ms][ns] = zf;

        short8b C2a[4], C2b[4];
        LOADC2(C2a, 0, 0);
        MMACP(0);
        LOADC2(C2b, 0, 1);
        MMAC2(C2a, 0, 0);
        LOADC2(C2a, 1, 0);
        MMACP(1);
        MMAC2(C2b, 0, 1);
        LOADC2(C2b, 1, 1);
        MMAC2(C2a, 1, 0);
        MMAC2(C2b, 1, 1);

        // ---- fused GRU epilogue (gi from LDS, fast exp/tanh) ----
#pragma unroll
        for (int ms = 0; ms < 2; ++ms)
#pragma unroll
            for (int i = 0; i < 4; ++i) {
                const int rl = ms * 16 + kg * 4 + i;
                const int nd = Nd[rl];
                if (nd < 0) continue;
#pragma unroll
                for (int ns = 0; ns < 2; ++ns) {
                    const int k = cb + ns * 16 + lr;
                    const int kc = k >> 3;
                    const int hp_off = (((kc & 24) | ((kc ^ rl) & 7)) << 3) + (k & 7);
                    float hp = bf2f(Ab[rl][hp_off]);
                    float xr = bf2f(Ag[rl][k])       + acc[0][ms][ns][i] + bh[0][ns];
                    float xz = bf2f(Ag[rl][256 + k]) + acc[1][ms][ns][i] + bh[1][ns];
                    float r = fsig(xr);
                    float z = fsig(xz);
                    float n = ftanh(bf2f(Ag[rl][512 + k]) +
                                    r * (acc[2][ms][ns][i] + bh[2][ns]));
                    float h = (1.0f - z) * n + z * hp;
                    if (d == 0) {
                        out[(size_t)(nd / S_NODES) * H_DIM + k] = h;
                    } else {
                        h_all[(size_t)nd * H_DIM + k] = f2bf(h);
                    }
                }
            }
    }
}

// ---------------------------------------------------------------------------
extern "C" void kernel_launch(void* const* d_in, const int* in_sizes, int n_in,
                              void* d_out, int out_size, void* d_ws, size_t ws_size,
                              hipStream_t stream) {
    const float* inputs = (const float*)d_in[0];
    const float* w_ih   = (const float*)d_in[1];
    const float* w_hh   = (const float*)d_in[2];
    const float* b_ih   = (const float*)d_in[3];
    const float* b_hh   = (const float*)d_in[4];
    const int* layer_nodes = (const int*)d_in[5];
    const int* child_idx   = (const int*)d_in[6];
    const int* child_cnt   = (const int*)d_in[7];

    const int LM = in_sizes[5];
    const int C  = in_sizes[6] / in_sizes[5];

    char* w = (char*)d_ws;
    size_t o = 0;
    auto alloc = [&](size_t bytes) {
        void* p = w + o;
        o += (bytes + 255) & ~(size_t)255;
        return p;
    };
    unsigned short* wib    = (unsigned short*)alloc((size_t)G_DIM * F_DIM * 2);
    unsigned short* whb    = (unsigned short*)alloc((size_t)G_DIM * H_DIM * 2);
    unsigned short* xb     = (unsigned short*)alloc((size_t)N_NODES * F_DIM * 2);
    unsigned short* h_all  = (unsigned short*)alloc((size_t)N_NODES * H_DIM * 2);
    unsigned short* gi_all = (unsigned short*)alloc((size_t)N_NODES * G_DIM * 2);
    int*            Mdev      = (int*)alloc(4);
    int*            layer_cnt = (int*)alloc(D_MAX * 4);
    (void)ws_size;

    hipMemsetAsync(Mdev, 0x7F, 4, stream);                 // 0x7F7F7F7F > LM
    hipMemsetAsync(layer_cnt, 0, D_MAX * 4, stream);

    k_zero<<<2048, 256, 0, stream>>>((float4*)h_all, N_NODES * H_DIM * 2 / 16);
    k_convx<<<2048, 256, 0, stream>>>(inputs, xb, N_NODES * F_DIM / 8);
    k_findM<<<256, 256, 0, stream>>>(layer_nodes, LM, Mdev);
    k_hist<<<256, 256, 0, stream>>>(layer_nodes, Mdev, layer_cnt, LM);
    k_convw<<<(G_DIM * F_DIM + 255) / 256, 256, 0, stream>>>(w_ih, w_hh, wib, whb);

    // One-shot feed-forward GEMM (b_ih folded in)
    k_gemm_x<<<(N_NODES + 127) / 128, 256, 0, stream>>>(xb, wib, b_ih, gi_all);

    // Depth layers, deepest first (empty layers exit immediately)
    for (int d = D_MAX - 1; d >= 0; --d)
        k_layer<<<512, 512, 0, stream>>>(layer_nodes, child_idx, child_cnt,
                                         Mdev, layer_cnt, whb, gi_all, b_hh,
                                         h_all, (float*)d_out, d, C);
}

// Round 12
// 996.564 us; speedup vs baseline: 1.5537x; 1.0450x over previous
//
#include <hip/hip_runtime.h>
#include <hip/hip_bf16.h>
#include <math.h>

#define N_NODES 200000
#define T_TREES 2000
#define S_NODES 100
#define F_DIM 256
#define H_DIM 256
#define G_DIM 768   // 3*H
#define D_MAX 28    // upper bound on depth layers (actual ~16)

typedef __attribute__((ext_vector_type(8))) short short8b;   // 8 bf16 = 4 VGPR
typedef __attribute__((ext_vector_type(4))) float f32x4;

static __device__ __forceinline__ unsigned short f2bf(float x) {
    union { __hip_bfloat16 h; unsigned short u; } cv;
    cv.h = __float2bfloat16(x);
    return cv.u;
}
static __device__ __forceinline__ float bf2f(unsigned short u) {
    return __uint_as_float(((unsigned)u) << 16);
}
// fast sigmoid/tanh via v_exp_f32 + v_rcp_f32 (overflow-safe forms)
static __device__ __forceinline__ float fsig(float x) {
    return __builtin_amdgcn_rcpf(1.0f + __expf(-x));
}
static __device__ __forceinline__ float ftanh(float x) {
    return 1.0f - 2.0f * __builtin_amdgcn_rcpf(__expf(2.0f * x) + 1.0f);
}

// ---------------------------------------------------------------------------
__global__ void k_zero(float4* __restrict__ p, int n4) {
    float4 z = make_float4(0.f, 0.f, 0.f, 0.f);
    for (int i = blockIdx.x * blockDim.x + threadIdx.x; i < n4;
         i += gridDim.x * blockDim.x)
        p[i] = z;
}

// M = min{ p >= T : layer_nodes[p] < N } (layer 0 is exactly the T roots)
__global__ void k_findM(const int* __restrict__ ln, int LM, int* __restrict__ Mdev) {
    int local = 0x7F7F7F7F;
    for (int p = T_TREES + blockIdx.x * blockDim.x + threadIdx.x; p < LM;
         p += gridDim.x * blockDim.x)
        if (ln[p] < N_NODES && p < local) local = p;
#pragma unroll
    for (int off = 32; off; off >>= 1) {
        int o = __shfl_down(local, off);
        if (o < local) local = o;
    }
    __shared__ int wmin[4];
    if ((threadIdx.x & 63) == 0) wmin[threadIdx.x >> 6] = local;
    __syncthreads();
    if (threadIdx.x == 0) {
        int m = wmin[0];
        for (int i = 1; i < 4; ++i) if (wmin[i] < m) m = wmin[i];
        if (m < 0x7F7F7F7F) atomicMin(Mdev, m);
    }
}

// layer_cnt[d] = #valid nodes in layer d (valid entries are a row prefix)
__global__ void k_hist(const int* __restrict__ ln, const int* __restrict__ Mdev,
                       int* __restrict__ layer_cnt, int LM) {
    __shared__ int h[D_MAX];
    if (threadIdx.x < D_MAX) h[threadIdx.x] = 0;
    __syncthreads();
    const int M = Mdev[0];
    for (int p = blockIdx.x * blockDim.x + threadIdx.x; p < LM;
         p += gridDim.x * blockDim.x)
        if (ln[p] < N_NODES) {
            int d = p / M;
            if (d < D_MAX) atomicAdd(&h[d], 1);
        }
    __syncthreads();
    if (threadIdx.x < D_MAX && h[threadIdx.x])
        atomicAdd(&layer_cnt[threadIdx.x], h[threadIdx.x]);
}

// Weights fp32 -> bf16 (row-major [g][k])
__global__ void k_convw(const float* __restrict__ wi, const float* __restrict__ wh,
                        unsigned short* __restrict__ wib, unsigned short* __restrict__ whb) {
    int i = blockIdx.x * blockDim.x + threadIdx.x;
    if (i < G_DIM * F_DIM) {
        wib[i] = f2bf(wi[i]);
        whb[i] = f2bf(wh[i]);
    }
}

// ---------------------------------------------------------------------------
// One-shot GEMM: gi_all[m][g] = (sum_k x[m][k] * w_ih[g][k]) + b_ih[g]  (bf16)
// x read as fp32 and converted in the A-load (once per block; k_convx removed).
// B staged in LDS double-buffered; 16B-chunk XOR swizzle with 3-bit row hash
// h(r) = (r&3)|(((r>>3)&1)<<2)  -> 2 lanes/bank-slot on reads (free).
// ---------------------------------------------------------------------------
__global__ __launch_bounds__(256) void k_gemm_x(
    const float* __restrict__ x,
    const unsigned short* __restrict__ wib,
    const float* __restrict__ b_ih,
    unsigned short* __restrict__ gi_all) {
    __shared__ unsigned short Bs[2][64][256];

    const int tid = threadIdx.x;
    const int wv = tid >> 6, lane = tid & 63;
    const int lr = lane & 15, kg = lane >> 4;
    const long m0 = (long)blockIdx.x * 128 + wv * 32;

    // A fragments: fp32 -> bf16 once per block, resident for all 12 tiles
    short8b A[2][8];
#pragma unroll
    for (int ms = 0; ms < 2; ++ms) {
        long r = m0 + ms * 16 + lr;
        if (r > N_NODES - 1) r = N_NODES - 1;
        const float* xp = x + r * F_DIM + kg * 8;
#pragma unroll
        for (int ks = 0; ks < 8; ++ks) {
            float4 u = *(const float4*)(xp + ks * 32);
            float4 v = *(const float4*)(xp + ks * 32 + 4);
            short8b t;
            t[0] = f2bf(u.x); t[1] = f2bf(u.y); t[2] = f2bf(u.z); t[3] = f2bf(u.w);
            t[4] = f2bf(v.x); t[5] = f2bf(v.y); t[6] = f2bf(v.z); t[7] = f2bf(v.w);
            A[ms][ks] = t;
        }
    }

    // staging: thread stages row sr, 4x(two 8-ushort chunks)
    const int sr = tid >> 2, sp = tid & 3;
    const int hs = (sr & 3) | (((sr >> 3) & 1) << 2);   // row hash
    // read rows: permuted for contiguous-g output; hash identical for P and Q
    const int gp_off = (lr >> 2) * 8 + (lr & 3);
    const int hq = (lr & 3) | (((lr >> 2) & 1) << 2);

    short8b st[8];
    // ---- prologue: stage tile 0 ----
    {
        const unsigned short* src = wib + (size_t)sr * F_DIM;
#pragma unroll
        for (int q = 0; q < 4; ++q) {
            int c = sp * 16 + q * 64;
            st[2 * q]     = *(const short8b*)(src + c);
            st[2 * q + 1] = *(const short8b*)(src + c + 8);
        }
#pragma unroll
        for (int q = 0; q < 4; ++q) {
            int c0 = sp * 2 + q * 8, c1 = c0 + 1;
            *(short8b*)&Bs[0][sr][((c0 & 24) | ((c0 ^ hs) & 7)) << 3] = st[2 * q];
            *(short8b*)&Bs[0][sr][((c1 & 24) | ((c1 ^ hs) & 7)) << 3] = st[2 * q + 1];
        }
    }
    __syncthreads();

    const f32x4 zf = {0.f, 0.f, 0.f, 0.f};

    for (int nt = 0; nt < 12; ++nt) {
        const int cur = nt & 1;
        // ---- issue next tile's global loads (land under MFMA) ----
        if (nt < 11) {
            const unsigned short* src = wib + (size_t)((nt + 1) * 64 + sr) * F_DIM;
#pragma unroll
            for (int q = 0; q < 4; ++q) {
                int c = sp * 16 + q * 64;
                st[2 * q]     = *(const short8b*)(src + c);
                st[2 * q + 1] = *(const short8b*)(src + c + 8);
            }
        }
        // ---- compute from Bs[cur] ----
#pragma unroll
        for (int nsp = 0; nsp < 2; ++nsp) {
            f32x4 aP0 = zf, aQ0 = zf, aP1 = zf, aQ1 = zf;
            const int rP = nsp * 32 + gp_off;
#pragma unroll
            for (int ks = 0; ks < 8; ++ks) {
                const int c = ks * 4 + kg;
                const int pc = ((c & 24) | ((c ^ hq) & 7)) << 3;
                short8b BP = *(const short8b*)&Bs[cur][rP][pc];
                short8b BQ = *(const short8b*)&Bs[cur][rP + 4][pc];
                aP0 = __builtin_amdgcn_mfma_f32_16x16x32_bf16(BP, A[0][ks], aP0, 0, 0, 0);
                aQ0 = __builtin_amdgcn_mfma_f32_16x16x32_bf16(BQ, A[0][ks], aQ0, 0, 0, 0);
                aP1 = __builtin_amdgcn_mfma_f32_16x16x32_bf16(BP, A[1][ks], aP1, 0, 0, 0);
                aQ1 = __builtin_amdgcn_mfma_f32_16x16x32_bf16(BQ, A[1][ks], aQ1, 0, 0, 0);
            }
            const int g0 = nt * 64 + nsp * 32 + kg * 8;
            f32x4 b0 = *(const f32x4*)(b_ih + g0);
            f32x4 b1 = *(const f32x4*)(b_ih + g0 + 4);
            long m = m0 + lr;
            if (m < N_NODES) {
                short8b pk;
#pragma unroll
                for (int i = 0; i < 4; ++i) {
                    pk[i]     = f2bf(aP0[i] + b0[i]);
                    pk[4 + i] = f2bf(aQ0[i] + b1[i]);
                }
                *(short8b*)(gi_all + m * G_DIM + g0) = pk;
            }
            m = m0 + 16 + lr;
            if (m < N_NODES) {
                short8b pk;
#pragma unroll
                for (int i = 0; i < 4; ++i) {
                    pk[i]     = f2bf(aP1[i] + b0[i]);
                    pk[4 + i] = f2bf(aQ1[i] + b1[i]);
                }
                *(short8b*)(gi_all + m * G_DIM + g0) = pk;
            }
        }
        // ---- write staged tile into the other buffer ----
        if (nt < 11) {
            __syncthreads();
#pragma unroll
            for (int q = 0; q < 4; ++q) {
                int c0 = sp * 2 + q * 8, c1 = c0 + 1;
                *(short8b*)&Bs[cur ^ 1][sr][((c0 & 24) | ((c0 ^ hs) & 7)) << 3] = st[2 * q];
                *(short8b*)&Bs[cur ^ 1][sr][((c1 & 24) | ((c1 ^ hs) & 7)) << 3] = st[2 * q + 1];
            }
            __syncthreads();
        }
    }
}

// ---------------------------------------------------------------------------
// One depth layer, v5 (unchanged from round 11): 512 thr / 8 waves /
// __launch_bounds__(512,2); r,z-gate whb fragments register-persistent across
// tiles; n-gate streamed in quarter-buffers; gi rows staged to LDS coalesced.
// ---------------------------------------------------------------------------
#define LOADC2(buf, ns_, kh_)                                                  \
  _Pragma("unroll")                                                            \
  for (int kk = 0; kk < 4; ++kk)                                               \
    buf[kk] = *(const short8b*)(whb +                                          \
        (size_t)(512 + cb + (ns_) * 16 + lr) * H_DIM + ((kh_) * 4 + kk) * 32 + kg * 8);

#define MMACP(c_)                                                              \
  _Pragma("unroll")                                                            \
  for (int ks = 0; ks < 8; ++ks) {                                             \
    const int cch = ks * 4 + kg;                                               \
    const int pc = ((cch & 24) | ((cch ^ lr) & 7)) << 3;                       \
    short8b A0 = *(const short8b*)&Ab[lr][pc];                                 \
    short8b A1 = *(const short8b*)&Ab[16 + lr][pc];                            \
    _Pragma("unroll")                                                          \
    for (int ns = 0; ns < 2; ++ns) {                                           \
      acc[c_][0][ns] = __builtin_amdgcn_mfma_f32_16x16x32_bf16(                \
          A0, Bp[c_][ns][ks], acc[c_][0][ns], 0, 0, 0);                        \
      acc[c_][1][ns] = __builtin_amdgcn_mfma_f32_16x16x32_bf16(                \
          A1, Bp[c_][ns][ks], acc[c_][1][ns], 0, 0, 0);                        \
    }                                                                          \
  }

#define MMAC2(buf, ns_, kh_)                                                   \
  _Pragma("unroll")                                                            \
  for (int kk = 0; kk < 4; ++kk) {                                             \
    const int ks = (kh_) * 4 + kk;                                             \
    const int cch = ks * 4 + kg;                                               \
    const int pc = ((cch & 24) | ((cch ^ lr) & 7)) << 3;                       \
    short8b A0 = *(const short8b*)&Ab[lr][pc];                                 \
    short8b A1 = *(const short8b*)&Ab[16 + lr][pc];                            \
    acc[2][0][ns_] = __builtin_amdgcn_mfma_f32_16x16x32_bf16(                  \
        A0, buf[kk], acc[2][0][ns_], 0, 0, 0);                                 \
    acc[2][1][ns_] = __builtin_amdgcn_mfma_f32_16x16x32_bf16(                  \
        A1, buf[kk], acc[2][1][ns_], 0, 0, 0);                                 \
  }

__global__ __launch_bounds__(512, 2) void k_layer(
    const int* __restrict__ layer_nodes,
    const int* __restrict__ child_idx,
    const int* __restrict__ child_cnt,
    const int* __restrict__ Mdev,
    const int* __restrict__ layer_cnt,
    const unsigned short* __restrict__ whb,
    const unsigned short* __restrict__ gi_all,
    const float* __restrict__ b_hh,
    unsigned short* __restrict__ h_all,
    float* __restrict__ out,
    int d, int C) {
    __shared__ unsigned short Ab[32][256];   // swizzled h_prev (16B chunks)
    __shared__ unsigned short Ag[32][776];   // gi rows (pitch 776 = 4 mod 32 dw)
    __shared__ int Nd[32];

    const int cntd = layer_cnt[d];
    if (cntd == 0) return;
    const int M = Mdev[0];
    const int ntiles = (cntd + 31) >> 5;
    if (blockIdx.x >= ntiles) return;
    const long pbase = (long)d * M;

    const int tid = threadIdx.x;
    const int wv = tid >> 6, lane = tid & 63;
    const int lr = lane & 15, kg = lane >> 4;
    const int cb = wv * 32;                 // col base within each 256-chunk

    // ---- persistent B fragments for gates r,z (c=0,1): loaded ONCE ----
    short8b Bp[2][2][8];
#pragma unroll
    for (int c = 0; c < 2; ++c)
#pragma unroll
        for (int ns = 0; ns < 2; ++ns) {
            const unsigned short* bp =
                whb + (size_t)(c * 256 + cb + ns * 16 + lr) * H_DIM + kg * 8;
#pragma unroll
            for (int ks = 0; ks < 8; ++ks)
                Bp[c][ns][ks] = *(const short8b*)(bp + ks * 32);
        }

    float bh[3][2];
#pragma unroll
    for (int c = 0; c < 3; ++c)
#pragma unroll
        for (int ns = 0; ns < 2; ++ns)
            bh[c][ns] = b_hh[c * 256 + cb + ns * 16 + lr];

    const int srow = tid >> 4;              // 0..31 staging row (16 thr/row)
    const int sc = tid & 15;

    for (int tile = blockIdx.x; tile < ntiles; tile += gridDim.x) {
        __syncthreads();   // previous tile's LDS reads done
        // ---- staging: copy gi row + gather h_prev ----
        {
            int idx = tile * 32 + srow;
            int node = (idx < cntd) ? layer_nodes[pbase + idx] : -1;
            if (sc == 0) Nd[srow] = node;
            {
                const unsigned short* gp =
                    gi_all + (size_t)(node >= 0 ? node : 0) * G_DIM;
#pragma unroll
                for (int pass = 0; pass < 6; ++pass) {
                    int col = sc * 8 + pass * 128;
                    *(short8b*)&Ag[srow][col] = *(const short8b*)(gp + col);
                }
            }
            int cc = 0;
            const int* ch = nullptr;
            if (node >= 0) {
                cc = child_cnt[pbase + idx];
                ch = child_idx + (size_t)(pbase + idx) * C;
            }
            float inv = 1.0f / (float)(cc > 0 ? cc : 1);
            float sum[16];
#pragma unroll
            for (int i = 0; i < 16; ++i) sum[i] = 0.f;
            for (int c = 0; c < cc; ++c) {
                int kid = ch[c];
                const unsigned short* hr = h_all + (size_t)kid * H_DIM + sc * 16;
                short8b v0 = *(const short8b*)hr;
                short8b v1 = *(const short8b*)(hr + 8);
#pragma unroll
                for (int i = 0; i < 8; ++i) {
                    sum[i]     += bf2f((unsigned short)v0[i]);
                    sum[8 + i] += bf2f((unsigned short)v1[i]);
                }
            }
            short8b q0, q1;
#pragma unroll
            for (int i = 0; i < 8; ++i) {
                q0[i] = f2bf(sum[i] * inv);
                q1[i] = f2bf(sum[8 + i] * inv);
            }
            const int g = srow & 7;
            const int c0 = 2 * sc, c1 = 2 * sc + 1;   // 16B chunk ids
            *(short8b*)&Ab[srow][((c0 & 24) | ((c0 ^ g) & 7)) << 3] = q0;
            *(short8b*)&Ab[srow][((c1 & 24) | ((c1 ^ g) & 7)) << 3] = q1;
        }
        __syncthreads();

        // ---- GEMM: persistent r,z + quarter-streamed n gate ----
        const f32x4 zf = {0.f, 0.f, 0.f, 0.f};
        f32x4 acc[3][2][2];
#pragma unroll
        for (int c = 0; c < 3; ++c)
#pragma unroll
            for (int ms = 0; ms < 2; ++ms)
#pragma unroll
                for (int ns = 0; ns < 2; ++ns) acc[c][ms][ns] = zf;

        short8b C2a[4], C2b[4];
        LOADC2(C2a, 0, 0);
        MMACP(0);
        LOADC2(C2b, 0, 1);
        MMAC2(C2a, 0, 0);
        LOADC2(C2a, 1, 0);
        MMACP(1);
        MMAC2(C2b, 0, 1);
        LOADC2(C2b, 1, 1);
        MMAC2(C2a, 1, 0);
        MMAC2(C2b, 1, 1);

        // ---- fused GRU epilogue (gi from LDS, fast exp/tanh) ----
#pragma unroll
        for (int ms = 0; ms < 2; ++ms)
#pragma unroll
            for (int i = 0; i < 4; ++i) {
                const int rl = ms * 16 + kg * 4 + i;
                const int nd = Nd[rl];
                if (nd < 0) continue;
#pragma unroll
                for (int ns = 0; ns < 2; ++ns) {
                    const int k = cb + ns * 16 + lr;
                    const int kc = k >> 3;
                    const int hp_off = (((kc & 24) | ((kc ^ rl) & 7)) << 3) + (k & 7);
                    float hp = bf2f(Ab[rl][hp_off]);
                    float xr = bf2f(Ag[rl][k])       + acc[0][ms][ns][i] + bh[0][ns];
                    float xz = bf2f(Ag[rl][256 + k]) + acc[1][ms][ns][i] + bh[1][ns];
                    float r = fsig(xr);
                    float z = fsig(xz);
                    float n = ftanh(bf2f(Ag[rl][512 + k]) +
                                    r * (acc[2][ms][ns][i] + bh[2][ns]));
                    float h = (1.0f - z) * n + z * hp;
                    if (d == 0) {
                        out[(size_t)(nd / S_NODES) * H_DIM + k] = h;
                    } else {
                        h_all[(size_t)nd * H_DIM + k] = f2bf(h);
                    }
                }
            }
    }
}

// ---------------------------------------------------------------------------
extern "C" void kernel_launch(void* const* d_in, const int* in_sizes, int n_in,
                              void* d_out, int out_size, void* d_ws, size_t ws_size,
                              hipStream_t stream) {
    const float* inputs = (const float*)d_in[0];
    const float* w_ih   = (const float*)d_in[1];
    const float* w_hh   = (const float*)d_in[2];
    const float* b_ih   = (const float*)d_in[3];
    const float* b_hh   = (const float*)d_in[4];
    const int* layer_nodes = (const int*)d_in[5];
    const int* child_idx   = (const int*)d_in[6];
    const int* child_cnt   = (const int*)d_in[7];

    const int LM = in_sizes[5];
    const int C  = in_sizes[6] / in_sizes[5];

    char* w = (char*)d_ws;
    size_t o = 0;
    auto alloc = [&](size_t bytes) {
        void* p = w + o;
        o += (bytes + 255) & ~(size_t)255;
        return p;
    };
    unsigned short* wib    = (unsigned short*)alloc((size_t)G_DIM * F_DIM * 2);
    unsigned short* whb    = (unsigned short*)alloc((size_t)G_DIM * H_DIM * 2);
    unsigned short* h_all  = (unsigned short*)alloc((size_t)N_NODES * H_DIM * 2);
    unsigned short* gi_all = (unsigned short*)alloc((size_t)N_NODES * G_DIM * 2);
    int*            Mdev      = (int*)alloc(4);
    int*            layer_cnt = (int*)alloc(D_MAX * 4);
    (void)ws_size;

    hipMemsetAsync(Mdev, 0x7F, 4, stream);                 // 0x7F7F7F7F > LM
    hipMemsetAsync(layer_cnt, 0, D_MAX * 4, stream);

    k_zero<<<2048, 256, 0, stream>>>((float4*)h_all, N_NODES * H_DIM * 2 / 16);
    k_findM<<<256, 256, 0, stream>>>(layer_nodes, LM, Mdev);
    k_hist<<<256, 256, 0, stream>>>(layer_nodes, Mdev, layer_cnt, LM);
    k_convw<<<(G_DIM * F_DIM + 255) / 256, 256, 0, stream>>>(w_ih, w_hh, wib, whb);

    // One-shot feed-forward GEMM (b_ih folded in; x converted in-kernel)
    k_gemm_x<<<(N_NODES + 127) / 128, 256, 0, stream>>>(inputs, wib, b_ih, gi_all);

    // Depth layers, deepest first (empty layers exit immediately)
    for (int d = D_MAX - 1; d >= 0; --d)
        k_layer<<<512, 512, 0, stream>>>(layer_nodes, child_idx, child_cnt,
                                         Mdev, layer_cnt, whb, gi_all, b_hh,
                                         h_all, (float*)d_out, d, C);
}